// Round 12
// baseline (152.738 us; speedup 1.0000x reference)
//
#include <hip/hip_runtime.h>
#include <math.h>

// Problem constants
#define N_BATCH 64
#define CIN 256
#define CR 128
#define T_IN 8
#define H_IN 16
#define W_IN 16
#define S1 2048          // T_IN*H_IN*W_IN
#define T2 4
#define H2 8
#define W2 8
#define S2 256           // T2*H2*W2
#define PT 4
#define PH 7
#define PW 7
#define EPSB 1e-5f

typedef __attribute__((ext_vector_type(8))) short bf16x8;
typedef __attribute__((ext_vector_type(4))) float f32x4;
typedef __attribute__((ext_vector_type(4))) unsigned int u32x4;
typedef __attribute__((ext_vector_type(8))) unsigned short ushort8;

__device__ __forceinline__ float hswish(float y) {
    float c = fminf(fmaxf(y + 3.0f, 0.0f), 6.0f);
    return y * c * (1.0f / 6.0f);
}

__device__ __forceinline__ unsigned int fbits(float x) {
    return __float_as_uint(x);
}

__device__ __forceinline__ unsigned int pkbf16(float lo, float hi) {
    return ((fbits(lo) + 0x8000u) >> 16) | ((fbits(hi) + 0x8000u) & 0xFFFF0000u);
}

// ---------------------------------------------------------------------------
// Prep: split w1 into bf16 hi/lo (fragment-coalesced layout) and zero pp.
// flat = ((((co>>4)*8 + (k>>5))*4 + ((k>>3)&3))*16 + (co&15))*8 + (k&7)
// ---------------------------------------------------------------------------
__global__ __launch_bounds__(256) void wsplit_kernel(
    const float* __restrict__ w1, unsigned short* __restrict__ whi,
    unsigned short* __restrict__ wlo, float* __restrict__ pp)
{
    int i = blockIdx.x * 256 + threadIdx.x;   // 0..32767
    int co = i >> 8;
    int k  = i & 255;
    float x = w1[i];
    unsigned int bx = fbits(x);
    unsigned int h = (bx + 0x8000u) & 0xFFFF0000u;
    float r = x - __uint_as_float(h);
    int flat = ((((co >> 4) * 8 + (k >> 5)) * 4 + ((k >> 3) & 3)) * 16 + (co & 15)) * 8 + (k & 7);
    whi[flat] = (unsigned short)(h >> 16);
    wlo[flat] = (unsigned short)((fbits(r) + 0x8000u) >> 16);
    pp[i] = 0.0f;   // zero pooled-partial [64n][128co][4sq]
}

// ---------------------------------------------------------------------------
// Kernel X: repack x fp32 [n][ci][s] -> xb8 bf16 [n][ci/8][s][8].
// Reads: 8 sequential row-streams, 256B/instruction; writes 1KB/instruction
// fully contiguous.  Pure streaming; removes the 8KB-strided k-gather from
// conv1's inner loop entirely.
// ---------------------------------------------------------------------------
__global__ __launch_bounds__(256) void xcvt_kernel(
    const float* __restrict__ x, unsigned short* __restrict__ xb8)
{
    int blk = blockIdx.x;          // n*32 + ci8
    int n   = blk >> 5;
    int ci8 = blk & 31;
    int t = threadIdx.x;
    const float* xr = x + ((size_t)n * CIN + ci8 * 8) * S1;
    unsigned short* ob = xb8 + (size_t)blk * S1 * 8;
    #pragma unroll
    for (int i = 0; i < 8; i++) {
        int s = i * 256 + t;
        float vj[8];
        #pragma unroll
        for (int j = 0; j < 8; j++)
            vj[j] = xr[(size_t)j * S1 + s];
        u32x4 pk;
        #pragma unroll
        for (int p = 0; p < 4; p++)
            pk[p] = pkbf16(vj[2 * p], vj[2 * p + 1]);
        *reinterpret_cast<u32x4*>(ob + (size_t)s * 8) = pk;
    }
}

// ---------------------------------------------------------------------------
// Kernel A v8: 1x1x1 conv 256->128 + BN1 + hswish, split-bf16 MFMA.
// B fragments load DIRECTLY from xb8 (k-contiguous per lane, dense across
// lanes, L3-resident).  No LDS, no barriers, no in-loop packing.
// Tile [128co][64s], 4 waves (2 co-halves x 2 s-halves), wave = 64co x 32s.
// Col map: s = s0 + hw*32 + 2*ln16 + fs  (v5 map -> u32 packed epilogue).
// ---------------------------------------------------------------------------
__global__ __launch_bounds__(256, 4) void conv1_mfma_kernel(
    const unsigned short* __restrict__ xb8,
    const unsigned short* __restrict__ whi, const unsigned short* __restrict__ wlo,
    const float* __restrict__ g, const float* __restrict__ b,
    const float* __restrict__ m, const float* __restrict__ v,
    unsigned short* __restrict__ h1b)
{
    int blk = blockIdx.x;
    int n  = blk >> 5;
    int s0 = (blk & 31) << 6;
    int tid = threadIdx.x;
    int wave = tid >> 6;
    int lane = tid & 63;
    int gl   = lane >> 4;          // 0..3 (k-octet within 32-k step)
    int ln16 = lane & 15;
    int hw   = wave & 1;           // wave's s-half (32 s)
    int wcoG = (wave >> 1) * 4;    // co-group base (16-co units)

    // lane's B base: plane (n*32 + gl), s = s0 + hw*32 + 2*ln16 (fs=0)
    const unsigned short* xb = xb8 +
        (((size_t)n * 32 + gl) * S1 + s0 + hw * 32 + 2 * ln16) * 8;

    f32x4 acc[4][2];
    #pragma unroll
    for (int i = 0; i < 4; i++) {
        acc[i][0] = (f32x4){0.f, 0.f, 0.f, 0.f};
        acc[i][1] = (f32x4){0.f, 0.f, 0.f, 0.f};
    }

    #pragma unroll
    for (int ks = 0; ks < 8; ks++) {
        // B fragments: 16B contiguous per lane, dense 512B across the fs pair
        bf16x8 B0 = *reinterpret_cast<const bf16x8*>(xb + (size_t)(ks * 4) * S1 * 8);
        bf16x8 B1 = *reinterpret_cast<const bf16x8*>(xb + (size_t)(ks * 4) * S1 * 8 + 8);
        // W fragments (L2-hot, fragment-coalesced 1KB per wave-instruction)
        bf16x8 Ah[4], Al[4];
        #pragma unroll
        for (int fc = 0; fc < 4; fc++) {
            int off = ((((wcoG + fc) * 8 + ks) * 4 + gl) * 16 + ln16) * 8;
            Ah[fc] = *reinterpret_cast<const bf16x8*>(whi + off);
            Al[fc] = *reinterpret_cast<const bf16x8*>(wlo + off);
        }
        // 32 MFMA
        #pragma unroll
        for (int fc = 0; fc < 4; fc++) {
            acc[fc][0] = __builtin_amdgcn_mfma_f32_16x16x32_bf16(Ah[fc], B0, acc[fc][0], 0, 0, 0);
            acc[fc][1] = __builtin_amdgcn_mfma_f32_16x16x32_bf16(Ah[fc], B1, acc[fc][1], 0, 0, 0);
        }
        #pragma unroll
        for (int fc = 0; fc < 4; fc++) {
            acc[fc][0] = __builtin_amdgcn_mfma_f32_16x16x32_bf16(Al[fc], B0, acc[fc][0], 0, 0, 0);
            acc[fc][1] = __builtin_amdgcn_mfma_f32_16x16x32_bf16(Al[fc], B1, acc[fc][1], 0, 0, 0);
        }
    }

    // --- epilogue: BN + hswish + packed bf16 store (fs0/fs1 = even/odd s) ---
    #pragma unroll
    for (int fc = 0; fc < 4; fc++)
        #pragma unroll
        for (int reg = 0; reg < 4; reg++) {
            int co = (wcoG + fc) * 16 + gl * 4 + reg;
            float sc_ = g[co] * rsqrtf(v[co] + EPSB);
            float tt = fmaf(-m[co], sc_, b[co]);
            float y0 = hswish(fmaf(acc[fc][0][reg], sc_, tt));
            float y1 = hswish(fmaf(acc[fc][1][reg], sc_, tt));
            unsigned int pk = pkbf16(y0, y1);
            *reinterpret_cast<unsigned int*>(
                h1b + ((size_t)n * CR + co) * S1 + s0 + hw * 32 + ln16 * 2) = pk;
        }
}

// ---------------------------------------------------------------------------
// Kernel B: depthwise 3x3x3 conv stride 2 pad 1 + BN2 + hswish (bf16 input)
// ---------------------------------------------------------------------------
__global__ __launch_bounds__(256) void dwconv_kernel(
    const unsigned short* __restrict__ h1b, const float* __restrict__ wdw,
    const float* __restrict__ g, const float* __restrict__ b,
    const float* __restrict__ m, const float* __restrict__ v,
    float* __restrict__ h2)
{
    __shared__ float s[T_IN][H_IN][W_IN];
    __shared__ float wl[27];
    int blk = blockIdx.x;
    int n = blk >> 7;
    int c = blk & 127;
    int tid = threadIdx.x;
    const unsigned short* in = h1b + ((size_t)n * CR + c) * S1;

    {
        int e = tid * 8;
        ushort8 u = *reinterpret_cast<const ushort8*>(in + e);
        float* sp = &s[0][0][0] + e;
        #pragma unroll
        for (int i = 0; i < 8; i++)
            sp[i] = __uint_as_float((unsigned int)(unsigned short)u[i] << 16);
    }
    if (tid < 27) wl[tid] = wdw[c * 27 + tid];
    __syncthreads();

    int wo = tid & 7;
    int ho = (tid >> 3) & 7;
    int to = tid >> 6;
    float acc = 0.0f;
    #pragma unroll
    for (int dt = 0; dt < 3; dt++) {
        int ti = 2 * to - 1 + dt;
        if (ti < 0 || ti >= T_IN) continue;
        #pragma unroll
        for (int dh = 0; dh < 3; dh++) {
            int hi = 2 * ho - 1 + dh;
            if (hi < 0 || hi >= H_IN) continue;
            #pragma unroll
            for (int dw = 0; dw < 3; dw++) {
                int wi = 2 * wo - 1 + dw;
                if (wi < 0 || wi >= W_IN) continue;
                acc = fmaf(wl[(dt * 3 + dh) * 3 + dw], s[ti][hi][wi], acc);
            }
        }
    }
    float sc = g[c] * rsqrtf(v[c] + EPSB);
    float y  = fmaf(acc, sc, fmaf(-m[c], sc, b[c]));
    h2[((size_t)n * CR + c) * S2 + tid] = hswish(y);
}

// ---------------------------------------------------------------------------
// Kernel C: 1x1x1 conv 128 -> 128 + BN3 + hswish, FUSED global-mean partials.
// ---------------------------------------------------------------------------
#define KC 16
__global__ __launch_bounds__(256) void conv2_kernel(
    const float* __restrict__ h2, const float* __restrict__ w2,
    const float* __restrict__ g, const float* __restrict__ b,
    const float* __restrict__ m, const float* __restrict__ v,
    float* __restrict__ pp)
{
    __shared__ float Xs[KC][64];
    __shared__ float Ws[KC][CR + 4];

    int blk = blockIdx.x;
    int n  = blk >> 2;
    int sq = blk & 3;
    int s0 = sq << 6;
    int tid = threadIdx.x;
    int tco = tid >> 3;
    int ts  = tid & 7;
    const float* xn = h2 + (size_t)n * CR * S2;

    float acc[4][8];
    #pragma unroll
    for (int i = 0; i < 4; i++)
        #pragma unroll
        for (int j = 0; j < 8; j++) acc[i][j] = 0.0f;

    for (int k0 = 0; k0 < CR; k0 += KC) {
        {
            int e  = tid * 4;
            int kk = e >> 6;
            int ss = e & 63;
            float4 xv = *reinterpret_cast<const float4*>(xn + (size_t)(k0 + kk) * S2 + s0 + ss);
            *reinterpret_cast<float4*>(&Xs[kk][ss]) = xv;
        }
        #pragma unroll
        for (int r = 0; r < 8; r++) {
            int e  = tid + r * 256;
            int co = e >> 4;
            int kk = e & 15;
            Ws[kk][co] = w2[co * CR + k0 + kk];
        }
        __syncthreads();
        #pragma unroll
        for (int kk = 0; kk < KC; kk++) {
            float a[4], bb[8];
            #pragma unroll
            for (int r = 0; r < 4; r++) a[r] = Ws[kk][tco * 4 + r];
            #pragma unroll
            for (int q = 0; q < 8; q++) bb[q] = Xs[kk][ts * 8 + q];
            #pragma unroll
            for (int r = 0; r < 4; r++)
                #pragma unroll
                for (int q = 0; q < 8; q++)
                    acc[r][q] = fmaf(a[r], bb[q], acc[r][q]);
        }
        __syncthreads();
    }

    #pragma unroll
    for (int r = 0; r < 4; r++) {
        int co = tco * 4 + r;
        float sc = g[co] * rsqrtf(v[co] + EPSB);
        float tt = fmaf(-m[co], sc, b[co]);
        float psum = 0.0f;
        #pragma unroll
        for (int q = 0; q < 8; q++)
            psum += hswish(fmaf(acc[r][q], sc, tt));
        #pragma unroll
        for (int off = 4; off > 0; off >>= 1)
            psum += __shfl_down(psum, off, 8);
        if (ts == 0)
            pp[((size_t)n * CR + co) * 4 + sq] = psum;
    }
}

// ---------------------------------------------------------------------------
// Kernel E: head — pooled mean from partials, 1x1 conv 128->6 + BN4 +
// sigmoid -> ROI boxes [n][6].  One block per n.
// ---------------------------------------------------------------------------
__global__ __launch_bounds__(128) void head_kernel(
    const float* __restrict__ pp, const float* __restrict__ w3,
    const float* __restrict__ g, const float* __restrict__ b,
    const float* __restrict__ m, const float* __restrict__ v,
    float* __restrict__ boxes)
{
    __shared__ float red[2];
    int n = blockIdx.x;
    int c = threadIdx.x;          // 0..127
    int wave = c >> 6, lane = c & 63;
    const float* p = pp + ((size_t)n * CR + c) * 4;
    float pc = (p[0] + p[1] + p[2] + p[3]) * (1.0f / 256.0f);

    for (int j = 0; j < 6; j++) {
        float t = w3[j * CR + c] * pc;
        #pragma unroll
        for (int off = 32; off > 0; off >>= 1)
            t += __shfl_down(t, off, 64);
        if (lane == 0) red[wave] = t;
        __syncthreads();
        if (c == 0) {
            float acc = red[0] + red[1];
            float sc = g[j] * rsqrtf(v[j] + EPSB);
            float logit = fmaf(acc, sc, fmaf(-m[j], sc, b[j]));
            float lim = 1.0f / (1.0f + expf(-logit));
            float scale = ((j % 3) == 2) ? 8.0f : 16.0f;
            float val = (j < 3) ? 0.5f * lim * scale : (1.0f - 0.5f * lim) * scale;
            boxes[n * 6 + j] = val;
        }
        __syncthreads();
    }
}

// ---------------------------------------------------------------------------
// Kernel F: 3D ROI align of x.  One block per (n,c); slice in LDS.
// ---------------------------------------------------------------------------
__global__ __launch_bounds__(256) void roi_kernel(
    const float* __restrict__ x, const float* __restrict__ boxes,
    float* __restrict__ out)
{
    __shared__ float s[T_IN][H_IN][W_IN];
    __shared__ float box[6];
    int blk = blockIdx.x;
    int n = blk >> 8;
    int c = blk & 255;
    int tid = threadIdx.x;
    const float* in = x + ((size_t)n * CIN + c) * S1;
    #pragma unroll
    for (int r = 0; r < 2; r++) {
        int e = (tid + r * 256) * 4;
        *reinterpret_cast<float4*>(&s[0][0][0] + e) =
            *reinterpret_cast<const float4*>(in + e);
    }
    if (tid < 6) box[tid] = boxes[n * 6 + tid];
    __syncthreads();

    if (tid < PT * PH * PW) {
        int pw = tid % 7;
        int ph = (tid / 7) % 7;
        int pt = tid / 49;
        float sx = box[0], sy = box[1], st = box[2];
        float bszx = fmaxf(box[3] - sx, 1.0f) * (1.0f / PW);
        float bszy = fmaxf(box[4] - sy, 1.0f) * (1.0f / PH);
        float bszt = fmaxf(box[5] - st, 1.0f) * (1.0f / PT);

        float acc = 0.0f;
        #pragma unroll
        for (int it = 0; it < 2; it++) {
            float tc = st + ((float)(pt * 2 + it) + 0.5f) * 0.5f * bszt;
            tc = fminf(fmaxf(tc, 0.0f), (float)(T_IN - 1));
            int tlo = (int)floorf(tc);
            int thi = min(tlo + 1, T_IN - 1);
            float tw = tc - (float)tlo;
            #pragma unroll
            for (int iy = 0; iy < 2; iy++) {
                float yc = sy + ((float)(ph * 2 + iy) + 0.5f) * 0.5f * bszy;
                yc = fminf(fmaxf(yc, 0.0f), (float)(H_IN - 1));
                int ylo = (int)floorf(yc);
                int yhi = min(ylo + 1, H_IN - 1);
                float yw = yc - (float)ylo;
                #pragma unroll
                for (int ix = 0; ix < 2; ix++) {
                    float xc = sx + ((float)(pw * 2 + ix) + 0.5f) * 0.5f * bszx;
                    xc = fminf(fmaxf(xc, 0.0f), (float)(W_IN - 1));
                    int xlo = (int)floorf(xc);
                    int xhi = min(xlo + 1, W_IN - 1);
                    float xw = xc - (float)xlo;

                    float v00 = s[tlo][ylo][xlo] * (1.0f - xw) + s[tlo][ylo][xhi] * xw;
                    float v01 = s[tlo][yhi][xlo] * (1.0f - xw) + s[tlo][yhi][xhi] * xw;
                    float v10 = s[thi][ylo][xlo] * (1.0f - xw) + s[thi][ylo][xhi] * xw;
                    float v11 = s[thi][yhi][xlo] * (1.0f - xw) + s[thi][yhi][xhi] * xw;
                    float v0 = v00 * (1.0f - yw) + v01 * yw;
                    float v1 = v10 * (1.0f - yw) + v11 * yw;
                    acc += v0 * (1.0f - tw) + v1 * tw;
                }
            }
        }
        out[(((size_t)(n * CIN + c) * PT + pt) * PH + ph) * PW + pw] = acc * 0.125f;
    }
}

// ---------------------------------------------------------------------------
extern "C" void kernel_launch(void* const* d_in, const int* in_sizes, int n_in,
                              void* d_out, int out_size, void* d_ws, size_t ws_size,
                              hipStream_t stream) {
    const float* x   = (const float*)d_in[0];
    const float* w1  = (const float*)d_in[1];
    const float* g1  = (const float*)d_in[2];
    const float* b1  = (const float*)d_in[3];
    const float* m1  = (const float*)d_in[4];
    const float* v1  = (const float*)d_in[5];
    const float* wdw = (const float*)d_in[6];
    const float* g2  = (const float*)d_in[7];
    const float* b2  = (const float*)d_in[8];
    const float* m2  = (const float*)d_in[9];
    const float* v2  = (const float*)d_in[10];
    const float* w2  = (const float*)d_in[11];
    const float* g3  = (const float*)d_in[12];
    const float* b3  = (const float*)d_in[13];
    const float* m3  = (const float*)d_in[14];
    const float* v3  = (const float*)d_in[15];
    const float* w3  = (const float*)d_in[16];
    const float* g4  = (const float*)d_in[17];
    const float* b4  = (const float*)d_in[18];
    const float* m4  = (const float*)d_in[19];
    const float* v4  = (const float*)d_in[20];

    // workspace layout (bytes): xb8 64MB | h1b 32MB | h2 8MB | whi/wlo 128KB
    //                           | pp 128KB | boxes
    unsigned short* xb8 = (unsigned short*)d_ws;                      // 33,554,432 u16
    unsigned short* h1b = xb8 + (size_t)N_BATCH * 32 * S1 * 8;        // 16,777,216 u16
    float* h2   = (float*)(h1b + (size_t)N_BATCH * CR * S1);          //  2,097,152 f
    unsigned short* whi = (unsigned short*)(h2 + (size_t)N_BATCH * CR * S2);  // 32768 u16
    unsigned short* wlo = whi + CR * CIN;                             // 32768 u16
    float* pp    = (float*)(wlo + CR * CIN);                          // 32768 f
    float* boxes = pp + (size_t)N_BATCH * CR * 4;                     // 384 f

    wsplit_kernel<<<dim3(128), dim3(256), 0, stream>>>(w1, whi, wlo, pp);
    xcvt_kernel<<<dim3(2048), dim3(256), 0, stream>>>(x, xb8);
    conv1_mfma_kernel<<<dim3(2048), dim3(256), 0, stream>>>(xb8, whi, wlo, g1, b1, m1, v1, h1b);
    dwconv_kernel<<<dim3(N_BATCH * CR), dim3(256), 0, stream>>>(h1b, wdw, g2, b2, m2, v2, h2);
    conv2_kernel<<<dim3(256), dim3(256), 0, stream>>>(h2, w2, g3, b3, m3, v3, pp);
    head_kernel<<<dim3(N_BATCH), dim3(128), 0, stream>>>(pp, w3, g4, b4, m4, v4, boxes);
    roi_kernel<<<dim3(N_BATCH * CIN), dim3(256), 0, stream>>>(x, boxes, (float*)d_out);
}

// Round 14
// 145.568 us; speedup vs baseline: 1.0493x; 1.0493x over previous
//
#include <hip/hip_runtime.h>
#include <math.h>

// Problem constants
#define N_BATCH 64
#define CIN 256
#define CR 128
#define T_IN 8
#define H_IN 16
#define W_IN 16
#define S1 2048          // T_IN*H_IN*W_IN
#define T2 4
#define H2 8
#define W2 8
#define S2 256           // T2*H2*W2
#define PT 4
#define PH 7
#define PW 7
#define EPSB 1e-5f

typedef __attribute__((ext_vector_type(8))) short bf16x8;
typedef __attribute__((ext_vector_type(4))) float f32x4;
typedef __attribute__((ext_vector_type(4))) unsigned int u32x4;
typedef __attribute__((ext_vector_type(8))) unsigned short ushort8;

__device__ __forceinline__ float hswish(float y) {
    float c = fminf(fmaxf(y + 3.0f, 0.0f), 6.0f);
    return y * c * (1.0f / 6.0f);
}

__device__ __forceinline__ unsigned int fbits(float x) {
    return __float_as_uint(x);
}

__device__ __forceinline__ unsigned int pkbf16(float lo, float hi) {
    return ((fbits(lo) + 0x8000u) >> 16) | ((fbits(hi) + 0x8000u) & 0xFFFF0000u);
}

// ---------------------------------------------------------------------------
// Prep: split w1 into bf16 hi/lo (fragment-coalesced layout) and zero pp.
// flat = ((((co>>4)*8 + (k>>5))*4 + ((k>>3)&3))*16 + (co&15))*8 + (k&7)
// ---------------------------------------------------------------------------
__global__ __launch_bounds__(256) void wsplit_kernel(
    const float* __restrict__ w1, unsigned short* __restrict__ whi,
    unsigned short* __restrict__ wlo, float* __restrict__ pp)
{
    int i = blockIdx.x * 256 + threadIdx.x;   // 0..32767
    int co = i >> 8;
    int k  = i & 255;
    float x = w1[i];
    unsigned int bx = fbits(x);
    unsigned int h = (bx + 0x8000u) & 0xFFFF0000u;
    float r = x - __uint_as_float(h);
    int flat = ((((co >> 4) * 8 + (k >> 5)) * 4 + ((k >> 3) & 3)) * 16 + (co & 15)) * 8 + (k & 7);
    whi[flat] = (unsigned short)(h >> 16);
    wlo[flat] = (unsigned short)((fbits(r) + 0x8000u) >> 16);
    pp[i] = 0.0f;   // zero pooled-partial [64n][128co][4sq]
}

// ---------------------------------------------------------------------------
// Kernel X: repack x fp32 [n][ci][s] -> xb8 bf16 [n][ci/8][s][8].
// Block reads one 64KB-contiguous region (8 adjacent rows), writes one
// 32KB-contiguous region.  Big-extent streaming on both sides.
// ---------------------------------------------------------------------------
__global__ __launch_bounds__(256) void xcvt_kernel(
    const float* __restrict__ x, unsigned short* __restrict__ xb8)
{
    int blk = blockIdx.x;          // n*32 + ci8
    int n   = blk >> 5;
    int ci8 = blk & 31;
    int t = threadIdx.x;
    const float* xr = x + ((size_t)n * CIN + ci8 * 8) * S1;
    unsigned short* ob = xb8 + (size_t)blk * S1 * 8;
    #pragma unroll
    for (int i = 0; i < 8; i++) {
        int s = i * 256 + t;
        float vj[8];
        #pragma unroll
        for (int j = 0; j < 8; j++)
            vj[j] = xr[(size_t)j * S1 + s];
        u32x4 pk;
        #pragma unroll
        for (int p = 0; p < 4; p++)
            pk[p] = pkbf16(vj[2 * p], vj[2 * p + 1]);
        *reinterpret_cast<u32x4*>(ob + (size_t)s * 8) = pk;
    }
}

// ---------------------------------------------------------------------------
// Kernel A v9: 1x1x1 conv 256->128 + BN1 + hswish, split-bf16 MFMA.
// BURST structure: each lane hoists ALL 16 B-fragment loads (8 ks x 2 frags,
// 64 VGPRs) from L3-hot xb8 BEFORE the K-loop -- one latency exposure per
// block instead of eight chained ones.  K-loop = L2-hot W loads + 32 MFMA.
// Tile [128co][64s], 4 waves (2 co-halves x 2 s-halves), wave = 64co x 32s.
// Col map: s = s0 + hw*32 + 2*ln16 + e  (packed-u32 epilogue unchanged).
// ---------------------------------------------------------------------------
__global__ __launch_bounds__(256, 2) void conv1_mfma_kernel(
    const unsigned short* __restrict__ xb8,
    const unsigned short* __restrict__ whi, const unsigned short* __restrict__ wlo,
    const float* __restrict__ g, const float* __restrict__ b,
    const float* __restrict__ m, const float* __restrict__ v,
    unsigned short* __restrict__ h1b)
{
    int blk = blockIdx.x;
    int n  = blk >> 5;
    int s0 = (blk & 31) << 6;
    int tid = threadIdx.x;
    int wave = tid >> 6;
    int lane = tid & 63;
    int gl   = lane >> 4;          // 0..3 (k-octet within 32-k step)
    int ln16 = lane & 15;
    int hw   = wave & 1;           // wave's s-half (32 s)
    int wcoG = (wave >> 1) * 4;    // co-group base (16-co units)

    // lane's B base: s = s0 + hw*32 + 2*ln16 (e=0); plane ci8 = ks*4 + gl
    const unsigned short* xb = xb8 +
        ((size_t)n * 32 * S1 + s0 + hw * 32 + 2 * ln16) * 8;

    // ---- BURST: all 16 B-fragment loads up front (one latency exposure) ----
    bf16x8 B[2][8];
    #pragma unroll
    for (int ks = 0; ks < 8; ks++) {
        size_t po = (size_t)(ks * 4 + gl) * S1 * 8;
        B[0][ks] = *reinterpret_cast<const bf16x8*>(xb + po);
        B[1][ks] = *reinterpret_cast<const bf16x8*>(xb + po + 8);
    }

    f32x4 acc[4][2];
    #pragma unroll
    for (int i = 0; i < 4; i++) {
        acc[i][0] = (f32x4){0.f, 0.f, 0.f, 0.f};
        acc[i][1] = (f32x4){0.f, 0.f, 0.f, 0.f};
    }

    #pragma unroll
    for (int ks = 0; ks < 8; ks++) {
        // W fragments (L2-hot, fragment-coalesced 1KB per wave-instruction)
        bf16x8 Ah[4], Al[4];
        #pragma unroll
        for (int fc = 0; fc < 4; fc++) {
            int off = ((((wcoG + fc) * 8 + ks) * 4 + gl) * 16 + ln16) * 8;
            Ah[fc] = *reinterpret_cast<const bf16x8*>(whi + off);
            Al[fc] = *reinterpret_cast<const bf16x8*>(wlo + off);
        }
        // 32 MFMA (register-resident B)
        #pragma unroll
        for (int fc = 0; fc < 4; fc++) {
            acc[fc][0] = __builtin_amdgcn_mfma_f32_16x16x32_bf16(Ah[fc], B[0][ks], acc[fc][0], 0, 0, 0);
            acc[fc][1] = __builtin_amdgcn_mfma_f32_16x16x32_bf16(Ah[fc], B[1][ks], acc[fc][1], 0, 0, 0);
        }
        #pragma unroll
        for (int fc = 0; fc < 4; fc++) {
            acc[fc][0] = __builtin_amdgcn_mfma_f32_16x16x32_bf16(Al[fc], B[0][ks], acc[fc][0], 0, 0, 0);
            acc[fc][1] = __builtin_amdgcn_mfma_f32_16x16x32_bf16(Al[fc], B[1][ks], acc[fc][1], 0, 0, 0);
        }
    }

    // --- epilogue: BN + hswish + packed bf16 store (e0/e1 = even/odd s) ---
    #pragma unroll
    for (int fc = 0; fc < 4; fc++)
        #pragma unroll
        for (int reg = 0; reg < 4; reg++) {
            int co = (wcoG + fc) * 16 + gl * 4 + reg;
            float sc_ = g[co] * rsqrtf(v[co] + EPSB);
            float tt = fmaf(-m[co], sc_, b[co]);
            float y0 = hswish(fmaf(acc[fc][0][reg], sc_, tt));
            float y1 = hswish(fmaf(acc[fc][1][reg], sc_, tt));
            unsigned int pk = pkbf16(y0, y1);
            *reinterpret_cast<unsigned int*>(
                h1b + ((size_t)n * CR + co) * S1 + s0 + hw * 32 + ln16 * 2) = pk;
        }
}

// ---------------------------------------------------------------------------
// Kernel B: depthwise 3x3x3 conv stride 2 pad 1 + BN2 + hswish (bf16 input)
// ---------------------------------------------------------------------------
__global__ __launch_bounds__(256) void dwconv_kernel(
    const unsigned short* __restrict__ h1b, const float* __restrict__ wdw,
    const float* __restrict__ g, const float* __restrict__ b,
    const float* __restrict__ m, const float* __restrict__ v,
    float* __restrict__ h2)
{
    __shared__ float s[T_IN][H_IN][W_IN];
    __shared__ float wl[27];
    int blk = blockIdx.x;
    int n = blk >> 7;
    int c = blk & 127;
    int tid = threadIdx.x;
    const unsigned short* in = h1b + ((size_t)n * CR + c) * S1;

    {
        int e = tid * 8;
        ushort8 u = *reinterpret_cast<const ushort8*>(in + e);
        float* sp = &s[0][0][0] + e;
        #pragma unroll
        for (int i = 0; i < 8; i++)
            sp[i] = __uint_as_float((unsigned int)(unsigned short)u[i] << 16);
    }
    if (tid < 27) wl[tid] = wdw[c * 27 + tid];
    __syncthreads();

    int wo = tid & 7;
    int ho = (tid >> 3) & 7;
    int to = tid >> 6;
    float acc = 0.0f;
    #pragma unroll
    for (int dt = 0; dt < 3; dt++) {
        int ti = 2 * to - 1 + dt;
        if (ti < 0 || ti >= T_IN) continue;
        #pragma unroll
        for (int dh = 0; dh < 3; dh++) {
            int hi = 2 * ho - 1 + dh;
            if (hi < 0 || hi >= H_IN) continue;
            #pragma unroll
            for (int dw = 0; dw < 3; dw++) {
                int wi = 2 * wo - 1 + dw;
                if (wi < 0 || wi >= W_IN) continue;
                acc = fmaf(wl[(dt * 3 + dh) * 3 + dw], s[ti][hi][wi], acc);
            }
        }
    }
    float sc = g[c] * rsqrtf(v[c] + EPSB);
    float y  = fmaf(acc, sc, fmaf(-m[c], sc, b[c]));
    h2[((size_t)n * CR + c) * S2 + tid] = hswish(y);
}

// ---------------------------------------------------------------------------
// Kernel C: 1x1x1 conv 128 -> 128 + BN3 + hswish, FUSED global-mean partials.
// ---------------------------------------------------------------------------
#define KC 16
__global__ __launch_bounds__(256) void conv2_kernel(
    const float* __restrict__ h2, const float* __restrict__ w2,
    const float* __restrict__ g, const float* __restrict__ b,
    const float* __restrict__ m, const float* __restrict__ v,
    float* __restrict__ pp)
{
    __shared__ float Xs[KC][64];
    __shared__ float Ws[KC][CR + 4];

    int blk = blockIdx.x;
    int n  = blk >> 2;
    int sq = blk & 3;
    int s0 = sq << 6;
    int tid = threadIdx.x;
    int tco = tid >> 3;
    int ts  = tid & 7;
    const float* xn = h2 + (size_t)n * CR * S2;

    float acc[4][8];
    #pragma unroll
    for (int i = 0; i < 4; i++)
        #pragma unroll
        for (int j = 0; j < 8; j++) acc[i][j] = 0.0f;

    for (int k0 = 0; k0 < CR; k0 += KC) {
        {
            int e  = tid * 4;
            int kk = e >> 6;
            int ss = e & 63;
            float4 xv = *reinterpret_cast<const float4*>(xn + (size_t)(k0 + kk) * S2 + s0 + ss);
            *reinterpret_cast<float4*>(&Xs[kk][ss]) = xv;
        }
        #pragma unroll
        for (int r = 0; r < 8; r++) {
            int e  = tid + r * 256;
            int co = e >> 4;
            int kk = e & 15;
            Ws[kk][co] = w2[co * CR + k0 + kk];
        }
        __syncthreads();
        #pragma unroll
        for (int kk = 0; kk < KC; kk++) {
            float a[4], bb[8];
            #pragma unroll
            for (int r = 0; r < 4; r++) a[r] = Ws[kk][tco * 4 + r];
            #pragma unroll
            for (int q = 0; q < 8; q++) bb[q] = Xs[kk][ts * 8 + q];
            #pragma unroll
            for (int r = 0; r < 4; r++)
                #pragma unroll
                for (int q = 0; q < 8; q++)
                    acc[r][q] = fmaf(a[r], bb[q], acc[r][q]);
        }
        __syncthreads();
    }

    #pragma unroll
    for (int r = 0; r < 4; r++) {
        int co = tco * 4 + r;
        float sc = g[co] * rsqrtf(v[co] + EPSB);
        float tt = fmaf(-m[co], sc, b[co]);
        float psum = 0.0f;
        #pragma unroll
        for (int q = 0; q < 8; q++)
            psum += hswish(fmaf(acc[r][q], sc, tt));
        #pragma unroll
        for (int off = 4; off > 0; off >>= 1)
            psum += __shfl_down(psum, off, 8);
        if (ts == 0)
            pp[((size_t)n * CR + co) * 4 + sq] = psum;
    }
}

// ---------------------------------------------------------------------------
// Kernel E: head — pooled mean from partials, 1x1 conv 128->6 + BN4 +
// sigmoid -> ROI boxes [n][6].  One block per n.
// ---------------------------------------------------------------------------
__global__ __launch_bounds__(128) void head_kernel(
    const float* __restrict__ pp, const float* __restrict__ w3,
    const float* __restrict__ g, const float* __restrict__ b,
    const float* __restrict__ m, const float* __restrict__ v,
    float* __restrict__ boxes)
{
    __shared__ float red[2];
    int n = blockIdx.x;
    int c = threadIdx.x;          // 0..127
    int wave = c >> 6, lane = c & 63;
    const float* p = pp + ((size_t)n * CR + c) * 4;
    float pc = (p[0] + p[1] + p[2] + p[3]) * (1.0f / 256.0f);

    for (int j = 0; j < 6; j++) {
        float t = w3[j * CR + c] * pc;
        #pragma unroll
        for (int off = 32; off > 0; off >>= 1)
            t += __shfl_down(t, off, 64);
        if (lane == 0) red[wave] = t;
        __syncthreads();
        if (c == 0) {
            float acc = red[0] + red[1];
            float sc = g[j] * rsqrtf(v[j] + EPSB);
            float logit = fmaf(acc, sc, fmaf(-m[j], sc, b[j]));
            float lim = 1.0f / (1.0f + expf(-logit));
            float scale = ((j % 3) == 2) ? 8.0f : 16.0f;
            float val = (j < 3) ? 0.5f * lim * scale : (1.0f - 0.5f * lim) * scale;
            boxes[n * 6 + j] = val;
        }
        __syncthreads();
    }
}

// ---------------------------------------------------------------------------
// Kernel F: 3D ROI align of x.  One block per (n,c); slice in LDS.
// ---------------------------------------------------------------------------
__global__ __launch_bounds__(256) void roi_kernel(
    const float* __restrict__ x, const float* __restrict__ boxes,
    float* __restrict__ out)
{
    __shared__ float s[T_IN][H_IN][W_IN];
    __shared__ float box[6];
    int blk = blockIdx.x;
    int n = blk >> 8;
    int c = blk & 255;
    int tid = threadIdx.x;
    const float* in = x + ((size_t)n * CIN + c) * S1;
    #pragma unroll
    for (int r = 0; r < 2; r++) {
        int e = (tid + r * 256) * 4;
        *reinterpret_cast<float4*>(&s[0][0][0] + e) =
            *reinterpret_cast<const float4*>(in + e);
    }
    if (tid < 6) box[tid] = boxes[n * 6 + tid];
    __syncthreads();

    if (tid < PT * PH * PW) {
        int pw = tid % 7;
        int ph = (tid / 7) % 7;
        int pt = tid / 49;
        float sx = box[0], sy = box[1], st = box[2];
        float bszx = fmaxf(box[3] - sx, 1.0f) * (1.0f / PW);
        float bszy = fmaxf(box[4] - sy, 1.0f) * (1.0f / PH);
        float bszt = fmaxf(box[5] - st, 1.0f) * (1.0f / PT);

        float acc = 0.0f;
        #pragma unroll
        for (int it = 0; it < 2; it++) {
            float tc = st + ((float)(pt * 2 + it) + 0.5f) * 0.5f * bszt;
            tc = fminf(fmaxf(tc, 0.0f), (float)(T_IN - 1));
            int tlo = (int)floorf(tc);
            int thi = min(tlo + 1, T_IN - 1);
            float tw = tc - (float)tlo;
            #pragma unroll
            for (int iy = 0; iy < 2; iy++) {
                float yc = sy + ((float)(ph * 2 + iy) + 0.5f) * 0.5f * bszy;
                yc = fminf(fmaxf(yc, 0.0f), (float)(H_IN - 1));
                int ylo = (int)floorf(yc);
                int yhi = min(ylo + 1, H_IN - 1);
                float yw = yc - (float)ylo;
                #pragma unroll
                for (int ix = 0; ix < 2; ix++) {
                    float xc = sx + ((float)(pw * 2 + ix) + 0.5f) * 0.5f * bszx;
                    xc = fminf(fmaxf(xc, 0.0f), (float)(W_IN - 1));
                    int xlo = (int)floorf(xc);
                    int xhi = min(xlo + 1, W_IN - 1);
                    float xw = xc - (float)xlo;

                    float v00 = s[tlo][ylo][xlo] * (1.0f - xw) + s[tlo][ylo][xhi] * xw;
                    float v01 = s[tlo][yhi][xlo] * (1.0f - xw) + s[tlo][yhi][xhi] * xw;
                    float v10 = s[thi][ylo][xlo] * (1.0f - xw) + s[thi][ylo][xhi] * xw;
                    float v11 = s[thi][yhi][xlo] * (1.0f - xw) + s[thi][yhi][xhi] * xw;
                    float v0 = v00 * (1.0f - yw) + v01 * yw;
                    float v1 = v10 * (1.0f - yw) + v11 * yw;
                    acc += v0 * (1.0f - tw) + v1 * tw;
                }
            }
        }
        out[(((size_t)(n * CIN + c) * PT + pt) * PH + ph) * PW + pw] = acc * 0.125f;
    }
}

// ---------------------------------------------------------------------------
extern "C" void kernel_launch(void* const* d_in, const int* in_sizes, int n_in,
                              void* d_out, int out_size, void* d_ws, size_t ws_size,
                              hipStream_t stream) {
    const float* x   = (const float*)d_in[0];
    const float* w1  = (const float*)d_in[1];
    const float* g1  = (const float*)d_in[2];
    const float* b1  = (const float*)d_in[3];
    const float* m1  = (const float*)d_in[4];
    const float* v1  = (const float*)d_in[5];
    const float* wdw = (const float*)d_in[6];
    const float* g2  = (const float*)d_in[7];
    const float* b2  = (const float*)d_in[8];
    const float* m2  = (const float*)d_in[9];
    const float* v2  = (const float*)d_in[10];
    const float* w2  = (const float*)d_in[11];
    const float* g3  = (const float*)d_in[12];
    const float* b3  = (const float*)d_in[13];
    const float* m3  = (const float*)d_in[14];
    const float* v3  = (const float*)d_in[15];
    const float* w3  = (const float*)d_in[16];
    const float* g4  = (const float*)d_in[17];
    const float* b4  = (const float*)d_in[18];
    const float* m4  = (const float*)d_in[19];
    const float* v4  = (const float*)d_in[20];

    // workspace layout (bytes): xb8 64MB | h1b 32MB | h2 8MB | whi/wlo 128KB
    //                           | pp 128KB | boxes
    unsigned short* xb8 = (unsigned short*)d_ws;                      // 33,554,432 u16
    unsigned short* h1b = xb8 + (size_t)N_BATCH * 32 * S1 * 8;        // 16,777,216 u16
    float* h2   = (float*)(h1b + (size_t)N_BATCH * CR * S1);          //  2,097,152 f
    unsigned short* whi = (unsigned short*)(h2 + (size_t)N_BATCH * CR * S2);  // 32768 u16
    unsigned short* wlo = whi + CR * CIN;                             // 32768 u16
    float* pp    = (float*)(wlo + CR * CIN);                          // 32768 f
    float* boxes = pp + (size_t)N_BATCH * CR * 4;                     // 384 f

    wsplit_kernel<<<dim3(128), dim3(256), 0, stream>>>(w1, whi, wlo, pp);
    xcvt_kernel<<<dim3(2048), dim3(256), 0, stream>>>(x, xb8);
    conv1_mfma_kernel<<<dim3(2048), dim3(256), 0, stream>>>(xb8, whi, wlo, g1, b1, m1, v1, h1b);
    dwconv_kernel<<<dim3(N_BATCH * CR), dim3(256), 0, stream>>>(h1b, wdw, g2, b2, m2, v2, h2);
    conv2_kernel<<<dim3(256), dim3(256), 0, stream>>>(h2, w2, g3, b3, m3, v3, pp);
    head_kernel<<<dim3(N_BATCH), dim3(128), 0, stream>>>(pp, w3, g4, b4, m4, v4, boxes);
    roi_kernel<<<dim3(N_BATCH * CIN), dim3(256), 0, stream>>>(x, boxes, (float*)d_out);
}

// Round 15
// 118.883 us; speedup vs baseline: 1.2848x; 1.2245x over previous
//
#include <hip/hip_runtime.h>
#include <math.h>

// Problem constants
#define N_BATCH 64
#define CIN 256
#define CR 128
#define T_IN 8
#define H_IN 16
#define W_IN 16
#define S1 2048          // T_IN*H_IN*W_IN
#define T2 4
#define H2 8
#define W2 8
#define S2 256           // T2*H2*W2
#define PT 4
#define PH 7
#define PW 7
#define EPSB 1e-5f

typedef __attribute__((ext_vector_type(8))) short bf16x8;
typedef __attribute__((ext_vector_type(4))) float f32x4;
typedef __attribute__((ext_vector_type(4))) unsigned int u32x4;
typedef __attribute__((ext_vector_type(8))) unsigned short ushort8;

__device__ __forceinline__ float hswish(float y) {
    float c = fminf(fmaxf(y + 3.0f, 0.0f), 6.0f);
    return y * c * (1.0f / 6.0f);
}

__device__ __forceinline__ unsigned int fbits(float x) {
    return __float_as_uint(x);
}

__device__ __forceinline__ unsigned int pkbf16(float lo, float hi) {
    return ((fbits(lo) + 0x8000u) >> 16) | ((fbits(hi) + 0x8000u) & 0xFFFF0000u);
}

// ---------------------------------------------------------------------------
// Prep: split w1 into bf16 hi/lo (fragment-coalesced layout) and zero pp.
// flat = ((((co>>4)*8 + (k>>5))*4 + ((k>>3)&3))*16 + (co&15))*8 + (k&7)
// ---------------------------------------------------------------------------
__global__ __launch_bounds__(256) void wsplit_kernel(
    const float* __restrict__ w1, unsigned short* __restrict__ whi,
    unsigned short* __restrict__ wlo, float* __restrict__ pp)
{
    int i = blockIdx.x * 256 + threadIdx.x;   // 0..32767
    int co = i >> 8;
    int k  = i & 255;
    float x = w1[i];
    unsigned int bx = fbits(x);
    unsigned int h = (bx + 0x8000u) & 0xFFFF0000u;
    float r = x - __uint_as_float(h);
    int flat = ((((co >> 4) * 8 + (k >> 5)) * 4 + ((k >> 3) & 3)) * 16 + (co & 15)) * 8 + (k & 7);
    whi[flat] = (unsigned short)(h >> 16);
    wlo[flat] = (unsigned short)((fbits(r) + 0x8000u) >> 16);
    pp[i] = 0.0f;   // zero pooled-partial [64n][128co][4sq]
}

// ---------------------------------------------------------------------------
// Kernel A v10: 1x1x1 conv 256->128 + BN1 + hswish, split-bf16 MFMA.
// HYBRID: W (hi+lo) preloaded to 128 VGPRs ONCE (contiguous gather from the
// fragment-coalesced layout) -- zero in-loop global loads on the critical
// path; x staged through pre-packed bf16 LDS fragments (v5) with DEPTH-2
// staging (v7).  Inner loop = 4 ds_read_b128 + 16 MFMA + pack + barrier.
// Tile [128co][64s], 4 waves; wave w covers co [32w,32w+32) x all 64 s.
// ---------------------------------------------------------------------------
#define BFIDX(g, h, e, ln) (((((g) * 2 + (h)) * 2 + (e)) * 16 + (ln)) * 4)

__global__ __launch_bounds__(256, 2) void conv1_mfma_kernel(
    const float* __restrict__ x,
    const unsigned short* __restrict__ whi, const unsigned short* __restrict__ wlo,
    const float* __restrict__ g, const float* __restrict__ b,
    const float* __restrict__ m, const float* __restrict__ v,
    unsigned short* __restrict__ h1b)
{
    __shared__ unsigned int Bf[2][1024];   // 2 x 4KB

    int blk = blockIdx.x;
    int n  = blk >> 5;
    int s0 = (blk & 31) << 6;
    int tid = threadIdx.x;
    int wave = tid >> 6;
    int lane = tid & 63;
    int gl   = lane >> 4;          // 0..3 (k-octet)
    int ln16 = lane & 15;

    // staging coords: thread covers k-octet sg, column sc (one s per thread)
    int sg = tid >> 6;             // 0..3
    int sc = tid & 63;             // s column 0..63
    int wslot = BFIDX(sg, sc >> 5, sc & 1, (sc & 31) >> 1);
    const float* xg = x + (size_t)n * CIN * S1 + s0 + sc;

    // ---- one-time W preload: 2fc x 8ks x (hi,lo) bf16x8 = 128 regs ----
    bf16x8 Ah[2][8], Al[2][8];
    #pragma unroll
    for (int fc = 0; fc < 2; fc++)
        #pragma unroll
        for (int ks = 0; ks < 8; ks++) {
            int coG = wave * 2 + fc;
            int off = (((coG * 8 + ks) * 4 + gl) * 16 + ln16) * 8;
            Ah[fc][ks] = *reinterpret_cast<const bf16x8*>(whi + off);
            Al[fc][ks] = *reinterpret_cast<const bf16x8*>(wlo + off);
        }

    f32x4 acc[2][4];
    #pragma unroll
    for (int i = 0; i < 2; i++)
        #pragma unroll
        for (int j = 0; j < 4; j++)
            acc[i][j] = (f32x4){0.f, 0.f, 0.f, 0.f};

    // ---- prologue: issue loads for ks=0,1; pack set0 -> Bf[0] ----
    float val[3][8];
    #pragma unroll
    for (int j = 0; j < 8; j++)
        val[0][j] = xg[(size_t)(sg * 8 + j) * S1];
    #pragma unroll
    for (int j = 0; j < 8; j++)
        val[1][j] = xg[(size_t)(32 + sg * 8 + j) * S1];
    {
        u32x4 wv;
        #pragma unroll
        for (int p = 0; p < 4; p++)
            wv[p] = pkbf16(val[0][2 * p], val[0][2 * p + 1]);
        *reinterpret_cast<u32x4*>(&Bf[0][wslot]) = wv;
    }
    __syncthreads();

    #pragma unroll
    for (int ks = 0; ks < 8; ks++) {
        // 1. issue x loads for ks+2 (in flight across this iter's pack wait)
        if (ks < 6) {
            #pragma unroll
            for (int j = 0; j < 8; j++)
                val[(ks + 2) % 3][j] = xg[(size_t)((ks + 2) * 32 + sg * 8 + j) * S1];
        }
        // 2. pack set ks+1 (loads issued one full iteration ago)
        if (ks < 7) {
            u32x4 wv;
            #pragma unroll
            for (int p = 0; p < 4; p++)
                wv[p] = pkbf16(val[(ks + 1) % 3][2 * p], val[(ks + 1) % 3][2 * p + 1]);
            *reinterpret_cast<u32x4*>(&Bf[(ks + 1) & 1][wslot]) = wv;
        }
        // 3. B fragments: 4 ds_read_b128; 16 MFMA (W register-resident)
        union { u32x4 u; bf16x8 bv; } B[4];
        #pragma unroll
        for (int fs = 0; fs < 4; fs++)
            B[fs].u = *reinterpret_cast<const u32x4*>(
                &Bf[ks & 1][BFIDX(gl, fs >> 1, fs & 1, ln16)]);
        #pragma unroll
        for (int fc = 0; fc < 2; fc++)
            #pragma unroll
            for (int fs = 0; fs < 4; fs++)
                acc[fc][fs] = __builtin_amdgcn_mfma_f32_16x16x32_bf16(
                    Ah[fc][ks], B[fs].bv, acc[fc][fs], 0, 0, 0);
        #pragma unroll
        for (int fc = 0; fc < 2; fc++)
            #pragma unroll
            for (int fs = 0; fs < 4; fs++)
                acc[fc][fs] = __builtin_amdgcn_mfma_f32_16x16x32_bf16(
                    Al[fc][ks], B[fs].bv, acc[fc][fs], 0, 0, 0);
        // 4. barrier: next buffer fully written
        if (ks < 7) __syncthreads();
    }

    // ---- epilogue: BN + hswish + packed bf16 stores ----
    // acc[fc][fs][reg] -> co = wave*32 + fc*16 + gl*4 + reg,
    //                     s  = s0 + (fs>>1)*32 + 2*ln16 + (fs&1)
    #pragma unroll
    for (int fc = 0; fc < 2; fc++)
        #pragma unroll
        for (int reg = 0; reg < 4; reg++) {
            int co = wave * 32 + fc * 16 + gl * 4 + reg;
            float sc_ = g[co] * rsqrtf(v[co] + EPSB);
            float tt = fmaf(-m[co], sc_, b[co]);
            float y0 = hswish(fmaf(acc[fc][0][reg], sc_, tt));
            float y1 = hswish(fmaf(acc[fc][1][reg], sc_, tt));
            float y2 = hswish(fmaf(acc[fc][2][reg], sc_, tt));
            float y3 = hswish(fmaf(acc[fc][3][reg], sc_, tt));
            unsigned short* o = h1b + ((size_t)n * CR + co) * S1 + s0;
            *reinterpret_cast<unsigned int*>(o + 2 * ln16)      = pkbf16(y0, y1);
            *reinterpret_cast<unsigned int*>(o + 32 + 2 * ln16) = pkbf16(y2, y3);
        }
}

// ---------------------------------------------------------------------------
// Kernel B: depthwise 3x3x3 conv stride 2 pad 1 + BN2 + hswish (bf16 input)
// ---------------------------------------------------------------------------
__global__ __launch_bounds__(256) void dwconv_kernel(
    const unsigned short* __restrict__ h1b, const float* __restrict__ wdw,
    const float* __restrict__ g, const float* __restrict__ b,
    const float* __restrict__ m, const float* __restrict__ v,
    float* __restrict__ h2)
{
    __shared__ float s[T_IN][H_IN][W_IN];
    __shared__ float wl[27];
    int blk = blockIdx.x;
    int n = blk >> 7;
    int c = blk & 127;
    int tid = threadIdx.x;
    const unsigned short* in = h1b + ((size_t)n * CR + c) * S1;

    {
        int e = tid * 8;
        ushort8 u = *reinterpret_cast<const ushort8*>(in + e);
        float* sp = &s[0][0][0] + e;
        #pragma unroll
        for (int i = 0; i < 8; i++)
            sp[i] = __uint_as_float((unsigned int)(unsigned short)u[i] << 16);
    }
    if (tid < 27) wl[tid] = wdw[c * 27 + tid];
    __syncthreads();

    int wo = tid & 7;
    int ho = (tid >> 3) & 7;
    int to = tid >> 6;
    float acc = 0.0f;
    #pragma unroll
    for (int dt = 0; dt < 3; dt++) {
        int ti = 2 * to - 1 + dt;
        if (ti < 0 || ti >= T_IN) continue;
        #pragma unroll
        for (int dh = 0; dh < 3; dh++) {
            int hi = 2 * ho - 1 + dh;
            if (hi < 0 || hi >= H_IN) continue;
            #pragma unroll
            for (int dw = 0; dw < 3; dw++) {
                int wi = 2 * wo - 1 + dw;
                if (wi < 0 || wi >= W_IN) continue;
                acc = fmaf(wl[(dt * 3 + dh) * 3 + dw], s[ti][hi][wi], acc);
            }
        }
    }
    float sc = g[c] * rsqrtf(v[c] + EPSB);
    float y  = fmaf(acc, sc, fmaf(-m[c], sc, b[c]));
    h2[((size_t)n * CR + c) * S2 + tid] = hswish(y);
}

// ---------------------------------------------------------------------------
// Kernel C: 1x1x1 conv 128 -> 128 + BN3 + hswish, FUSED global-mean partials.
// ---------------------------------------------------------------------------
#define KC 16
__global__ __launch_bounds__(256) void conv2_kernel(
    const float* __restrict__ h2, const float* __restrict__ w2,
    const float* __restrict__ g, const float* __restrict__ b,
    const float* __restrict__ m, const float* __restrict__ v,
    float* __restrict__ pp)
{
    __shared__ float Xs[KC][64];
    __shared__ float Ws[KC][CR + 4];

    int blk = blockIdx.x;
    int n  = blk >> 2;
    int sq = blk & 3;
    int s0 = sq << 6;
    int tid = threadIdx.x;
    int tco = tid >> 3;
    int ts  = tid & 7;
    const float* xn = h2 + (size_t)n * CR * S2;

    float acc[4][8];
    #pragma unroll
    for (int i = 0; i < 4; i++)
        #pragma unroll
        for (int j = 0; j < 8; j++) acc[i][j] = 0.0f;

    for (int k0 = 0; k0 < CR; k0 += KC) {
        {
            int e  = tid * 4;
            int kk = e >> 6;
            int ss = e & 63;
            float4 xv = *reinterpret_cast<const float4*>(xn + (size_t)(k0 + kk) * S2 + s0 + ss);
            *reinterpret_cast<float4*>(&Xs[kk][ss]) = xv;
        }
        #pragma unroll
        for (int r = 0; r < 8; r++) {
            int e  = tid + r * 256;
            int co = e >> 4;
            int kk = e & 15;
            Ws[kk][co] = w2[co * CR + k0 + kk];
        }
        __syncthreads();
        #pragma unroll
        for (int kk = 0; kk < KC; kk++) {
            float a[4], bb[8];
            #pragma unroll
            for (int r = 0; r < 4; r++) a[r] = Ws[kk][tco * 4 + r];
            #pragma unroll
            for (int q = 0; q < 8; q++) bb[q] = Xs[kk][ts * 8 + q];
            #pragma unroll
            for (int r = 0; r < 4; r++)
                #pragma unroll
                for (int q = 0; q < 8; q++)
                    acc[r][q] = fmaf(a[r], bb[q], acc[r][q]);
        }
        __syncthreads();
    }

    #pragma unroll
    for (int r = 0; r < 4; r++) {
        int co = tco * 4 + r;
        float sc = g[co] * rsqrtf(v[co] + EPSB);
        float tt = fmaf(-m[co], sc, b[co]);
        float psum = 0.0f;
        #pragma unroll
        for (int q = 0; q < 8; q++)
            psum += hswish(fmaf(acc[r][q], sc, tt));
        #pragma unroll
        for (int off = 4; off > 0; off >>= 1)
            psum += __shfl_down(psum, off, 8);
        if (ts == 0)
            pp[((size_t)n * CR + co) * 4 + sq] = psum;
    }
}

// ---------------------------------------------------------------------------
// Kernel E: head — pooled mean from partials, 1x1 conv 128->6 + BN4 +
// sigmoid -> ROI boxes [n][6].  One block per n.
// ---------------------------------------------------------------------------
__global__ __launch_bounds__(128) void head_kernel(
    const float* __restrict__ pp, const float* __restrict__ w3,
    const float* __restrict__ g, const float* __restrict__ b,
    const float* __restrict__ m, const float* __restrict__ v,
    float* __restrict__ boxes)
{
    __shared__ float red[2];
    int n = blockIdx.x;
    int c = threadIdx.x;          // 0..127
    int wave = c >> 6, lane = c & 63;
    const float* p = pp + ((size_t)n * CR + c) * 4;
    float pc = (p[0] + p[1] + p[2] + p[3]) * (1.0f / 256.0f);

    for (int j = 0; j < 6; j++) {
        float t = w3[j * CR + c] * pc;
        #pragma unroll
        for (int off = 32; off > 0; off >>= 1)
            t += __shfl_down(t, off, 64);
        if (lane == 0) red[wave] = t;
        __syncthreads();
        if (c == 0) {
            float acc = red[0] + red[1];
            float sc = g[j] * rsqrtf(v[j] + EPSB);
            float logit = fmaf(acc, sc, fmaf(-m[j], sc, b[j]));
            float lim = 1.0f / (1.0f + expf(-logit));
            float scale = ((j % 3) == 2) ? 8.0f : 16.0f;
            float val = (j < 3) ? 0.5f * lim * scale : (1.0f - 0.5f * lim) * scale;
            boxes[n * 6 + j] = val;
        }
        __syncthreads();
    }
}

// ---------------------------------------------------------------------------
// Kernel F: 3D ROI align of x.  One block per (n,c); slice in LDS.
// ---------------------------------------------------------------------------
__global__ __launch_bounds__(256) void roi_kernel(
    const float* __restrict__ x, const float* __restrict__ boxes,
    float* __restrict__ out)
{
    __shared__ float s[T_IN][H_IN][W_IN];
    __shared__ float box[6];
    int blk = blockIdx.x;
    int n = blk >> 8;
    int c = blk & 255;
    int tid = threadIdx.x;
    const float* in = x + ((size_t)n * CIN + c) * S1;
    #pragma unroll
    for (int r = 0; r < 2; r++) {
        int e = (tid + r * 256) * 4;
        *reinterpret_cast<float4*>(&s[0][0][0] + e) =
            *reinterpret_cast<const float4*>(in + e);
    }
    if (tid < 6) box[tid] = boxes[n * 6 + tid];
    __syncthreads();

    if (tid < PT * PH * PW) {
        int pw = tid % 7;
        int ph = (tid / 7) % 7;
        int pt = tid / 49;
        float sx = box[0], sy = box[1], st = box[2];
        float bszx = fmaxf(box[3] - sx, 1.0f) * (1.0f / PW);
        float bszy = fmaxf(box[4] - sy, 1.0f) * (1.0f / PH);
        float bszt = fmaxf(box[5] - st, 1.0f) * (1.0f / PT);

        float acc = 0.0f;
        #pragma unroll
        for (int it = 0; it < 2; it++) {
            float tc = st + ((float)(pt * 2 + it) + 0.5f) * 0.5f * bszt;
            tc = fminf(fmaxf(tc, 0.0f), (float)(T_IN - 1));
            int tlo = (int)floorf(tc);
            int thi = min(tlo + 1, T_IN - 1);
            float tw = tc - (float)tlo;
            #pragma unroll
            for (int iy = 0; iy < 2; iy++) {
                float yc = sy + ((float)(ph * 2 + iy) + 0.5f) * 0.5f * bszy;
                yc = fminf(fmaxf(yc, 0.0f), (float)(H_IN - 1));
                int ylo = (int)floorf(yc);
                int yhi = min(ylo + 1, H_IN - 1);
                float yw = yc - (float)ylo;
                #pragma unroll
                for (int ix = 0; ix < 2; ix++) {
                    float xc = sx + ((float)(pw * 2 + ix) + 0.5f) * 0.5f * bszx;
                    xc = fminf(fmaxf(xc, 0.0f), (float)(W_IN - 1));
                    int xlo = (int)floorf(xc);
                    int xhi = min(xlo + 1, W_IN - 1);
                    float xw = xc - (float)xlo;

                    float v00 = s[tlo][ylo][xlo] * (1.0f - xw) + s[tlo][ylo][xhi] * xw;
                    float v01 = s[tlo][yhi][xlo] * (1.0f - xw) + s[tlo][yhi][xhi] * xw;
                    float v10 = s[thi][ylo][xlo] * (1.0f - xw) + s[thi][ylo][xhi] * xw;
                    float v11 = s[thi][yhi][xlo] * (1.0f - xw) + s[thi][yhi][xhi] * xw;
                    float v0 = v00 * (1.0f - yw) + v01 * yw;
                    float v1 = v10 * (1.0f - yw) + v11 * yw;
                    acc += v0 * (1.0f - tw) + v1 * tw;
                }
            }
        }
        out[(((size_t)(n * CIN + c) * PT + pt) * PH + ph) * PW + pw] = acc * 0.125f;
    }
}

// ---------------------------------------------------------------------------
extern "C" void kernel_launch(void* const* d_in, const int* in_sizes, int n_in,
                              void* d_out, int out_size, void* d_ws, size_t ws_size,
                              hipStream_t stream) {
    const float* x   = (const float*)d_in[0];
    const float* w1  = (const float*)d_in[1];
    const float* g1  = (const float*)d_in[2];
    const float* b1  = (const float*)d_in[3];
    const float* m1  = (const float*)d_in[4];
    const float* v1  = (const float*)d_in[5];
    const float* wdw = (const float*)d_in[6];
    const float* g2  = (const float*)d_in[7];
    const float* b2  = (const float*)d_in[8];
    const float* m2  = (const float*)d_in[9];
    const float* v2  = (const float*)d_in[10];
    const float* w2  = (const float*)d_in[11];
    const float* g3  = (const float*)d_in[12];
    const float* b3  = (const float*)d_in[13];
    const float* m3  = (const float*)d_in[14];
    const float* v3  = (const float*)d_in[15];
    const float* w3  = (const float*)d_in[16];
    const float* g4  = (const float*)d_in[17];
    const float* b4  = (const float*)d_in[18];
    const float* m4  = (const float*)d_in[19];
    const float* v4  = (const float*)d_in[20];

    float* ws = (float*)d_ws;
    float* h1     = ws;                                   // bf16 h1 (ushort)
    float* h2     = h1 + (size_t)N_BATCH * CR * S1;       // 2,097,152 f
    float* h3     = h2 + (size_t)N_BATCH * CR * S2;       // region reused for whi/wlo
    float* pp     = h3 + (size_t)N_BATCH * CR * S2;       // 32,768 f pooled partials
    float* boxes  = pp + (size_t)N_BATCH * CR * 4;        // 384 f
    unsigned short* h1b = (unsigned short*)h1;
    unsigned short* whi = (unsigned short*)h3;            // 32768 u16
    unsigned short* wlo = whi + CR * CIN;                 // 32768 u16

    wsplit_kernel<<<dim3(128), dim3(256), 0, stream>>>(w1, whi, wlo, pp);
    conv1_mfma_kernel<<<dim3(2048), dim3(256), 0, stream>>>(x, whi, wlo, g1, b1, m1, v1, h1b);
    dwconv_kernel<<<dim3(N_BATCH * CR), dim3(256), 0, stream>>>(h1b, wdw, g2, b2, m2, v2, h2);
    conv2_kernel<<<dim3(256), dim3(256), 0, stream>>>(h2, w2, g3, b3, m3, v3, pp);
    head_kernel<<<dim3(N_BATCH), dim3(128), 0, stream>>>(pp, w3, g4, b4, m4, v4, boxes);
    roi_kernel<<<dim3(N_BATCH * CIN), dim3(256), 0, stream>>>(x, boxes, (float*)d_out);
}

// Round 16
// 115.718 us; speedup vs baseline: 1.3199x; 1.0274x over previous
//
#include <hip/hip_runtime.h>
#include <math.h>

// Problem constants
#define N_BATCH 64
#define CIN 256
#define CR 128
#define T_IN 8
#define H_IN 16
#define W_IN 16
#define S1 2048          // T_IN*H_IN*W_IN
#define T2 4
#define H2 8
#define W2 8
#define S2 256           // T2*H2*W2
#define PT 4
#define PH 7
#define PW 7
#define EPSB 1e-5f

typedef __attribute__((ext_vector_type(8))) short bf16x8;
typedef __attribute__((ext_vector_type(4))) float f32x4;
typedef __attribute__((ext_vector_type(4))) unsigned int u32x4;
typedef __attribute__((ext_vector_type(8))) unsigned short ushort8;

__device__ __forceinline__ float hswish(float y) {
    float c = fminf(fmaxf(y + 3.0f, 0.0f), 6.0f);
    return y * c * (1.0f / 6.0f);
}

__device__ __forceinline__ unsigned int fbits(float x) {
    return __float_as_uint(x);
}

__device__ __forceinline__ unsigned int pkbf16(float lo, float hi) {
    return ((fbits(lo) + 0x8000u) >> 16) | ((fbits(hi) + 0x8000u) & 0xFFFF0000u);
}

// ---------------------------------------------------------------------------
// Prep: split w1 into bf16 hi/lo (fragment-coalesced layout) and zero pp.
// flat = ((((co>>4)*8 + (k>>5))*4 + ((k>>3)&3))*16 + (co&15))*8 + (k&7)
// ---------------------------------------------------------------------------
__global__ __launch_bounds__(256) void wsplit_kernel(
    const float* __restrict__ w1, unsigned short* __restrict__ whi,
    unsigned short* __restrict__ wlo, float* __restrict__ pp)
{
    int i = blockIdx.x * 256 + threadIdx.x;   // 0..32767
    int co = i >> 8;
    int k  = i & 255;
    float x = w1[i];
    unsigned int bx = fbits(x);
    unsigned int h = (bx + 0x8000u) & 0xFFFF0000u;
    float r = x - __uint_as_float(h);
    int flat = ((((co >> 4) * 8 + (k >> 5)) * 4 + ((k >> 3) & 3)) * 16 + (co & 15)) * 8 + (k & 7);
    whi[flat] = (unsigned short)(h >> 16);
    wlo[flat] = (unsigned short)((fbits(r) + 0x8000u) >> 16);
    pp[i] = 0.0f;   // zero pooled-partial [64n][128co][4sq]
}

// ---------------------------------------------------------------------------
// Kernel A v11: 1x1x1 conv 256->128 + BN1 + hswish, split-bf16 MFMA.
// v10 structure with the occupancy cap lifted (LB 256,4): W fragments
// loaded per-iteration (the compiler sinks any preload anyway at this
// pressure); x staged through pre-packed bf16 LDS fragments with DEPTH-2
// staging.  Inner loop = 4 ds_read_b128 + W loads + 16+16 MFMA + pack.
// Tile [128co][64s], 4 waves; wave w covers co [32w,32w+32) x all 64 s.
// ---------------------------------------------------------------------------
#define BFIDX(g, h, e, ln) (((((g) * 2 + (h)) * 2 + (e)) * 16 + (ln)) * 4)

__global__ __launch_bounds__(256, 4) void conv1_mfma_kernel(
    const float* __restrict__ x,
    const unsigned short* __restrict__ whi, const unsigned short* __restrict__ wlo,
    const float* __restrict__ g, const float* __restrict__ b,
    const float* __restrict__ m, const float* __restrict__ v,
    unsigned short* __restrict__ h1b)
{
    __shared__ unsigned int Bf[2][1024];   // 2 x 4KB

    int blk = blockIdx.x;
    int n  = blk >> 5;
    int s0 = (blk & 31) << 6;
    int tid = threadIdx.x;
    int wave = tid >> 6;
    int lane = tid & 63;
    int gl   = lane >> 4;          // 0..3 (k-octet)
    int ln16 = lane & 15;

    // staging coords: thread covers k-octet sg, column sc (one s per thread)
    int sg = tid >> 6;             // 0..3
    int sc = tid & 63;             // s column 0..63
    int wslot = BFIDX(sg, sc >> 5, sc & 1, (sc & 31) >> 1);
    const float* xg = x + (size_t)n * CIN * S1 + s0 + sc;

    f32x4 acc[2][4];
    #pragma unroll
    for (int i = 0; i < 2; i++)
        #pragma unroll
        for (int j = 0; j < 4; j++)
            acc[i][j] = (f32x4){0.f, 0.f, 0.f, 0.f};

    // ---- prologue: issue loads for ks=0,1; pack set0 -> Bf[0] ----
    float val[3][8];
    #pragma unroll
    for (int j = 0; j < 8; j++)
        val[0][j] = xg[(size_t)(sg * 8 + j) * S1];
    #pragma unroll
    for (int j = 0; j < 8; j++)
        val[1][j] = xg[(size_t)(32 + sg * 8 + j) * S1];
    {
        u32x4 wv;
        #pragma unroll
        for (int p = 0; p < 4; p++)
            wv[p] = pkbf16(val[0][2 * p], val[0][2 * p + 1]);
        *reinterpret_cast<u32x4*>(&Bf[0][wslot]) = wv;
    }
    __syncthreads();

    #pragma unroll
    for (int ks = 0; ks < 8; ks++) {
        // 1. W fragments for this ks (L2-hot, coalesced 1KB/wave-instr)
        bf16x8 Ah[2], Al[2];
        #pragma unroll
        for (int fc = 0; fc < 2; fc++) {
            int coG = wave * 2 + fc;
            int off = (((coG * 8 + ks) * 4 + gl) * 16 + ln16) * 8;
            Ah[fc] = *reinterpret_cast<const bf16x8*>(whi + off);
            Al[fc] = *reinterpret_cast<const bf16x8*>(wlo + off);
        }
        // 2. issue x loads for ks+2 (in flight across this iter's pack wait)
        if (ks < 6) {
            #pragma unroll
            for (int j = 0; j < 8; j++)
                val[(ks + 2) % 3][j] = xg[(size_t)((ks + 2) * 32 + sg * 8 + j) * S1];
        }
        // 3. pack set ks+1 (loads issued one full iteration ago)
        if (ks < 7) {
            u32x4 wv;
            #pragma unroll
            for (int p = 0; p < 4; p++)
                wv[p] = pkbf16(val[(ks + 1) % 3][2 * p], val[(ks + 1) % 3][2 * p + 1]);
            *reinterpret_cast<u32x4*>(&Bf[(ks + 1) & 1][wslot]) = wv;
        }
        // 4. B fragments: 4 ds_read_b128; 16+16 MFMA
        union { u32x4 u; bf16x8 bv; } B[4];
        #pragma unroll
        for (int fs = 0; fs < 4; fs++)
            B[fs].u = *reinterpret_cast<const u32x4*>(
                &Bf[ks & 1][BFIDX(gl, fs >> 1, fs & 1, ln16)]);
        #pragma unroll
        for (int fc = 0; fc < 2; fc++)
            #pragma unroll
            for (int fs = 0; fs < 4; fs++)
                acc[fc][fs] = __builtin_amdgcn_mfma_f32_16x16x32_bf16(
                    Ah[fc], B[fs].bv, acc[fc][fs], 0, 0, 0);
        #pragma unroll
        for (int fc = 0; fc < 2; fc++)
            #pragma unroll
            for (int fs = 0; fs < 4; fs++)
                acc[fc][fs] = __builtin_amdgcn_mfma_f32_16x16x32_bf16(
                    Al[fc], B[fs].bv, acc[fc][fs], 0, 0, 0);
        // 5. barrier: next buffer fully written
        if (ks < 7) __syncthreads();
    }

    // ---- epilogue: BN + hswish + packed bf16 stores ----
    // acc[fc][fs][reg] -> co = wave*32 + fc*16 + gl*4 + reg,
    //                     s  = s0 + (fs>>1)*32 + 2*ln16 + (fs&1)
    #pragma unroll
    for (int fc = 0; fc < 2; fc++)
        #pragma unroll
        for (int reg = 0; reg < 4; reg++) {
            int co = wave * 32 + fc * 16 + gl * 4 + reg;
            float sc_ = g[co] * rsqrtf(v[co] + EPSB);
            float tt = fmaf(-m[co], sc_, b[co]);
            float y0 = hswish(fmaf(acc[fc][0][reg], sc_, tt));
            float y1 = hswish(fmaf(acc[fc][1][reg], sc_, tt));
            float y2 = hswish(fmaf(acc[fc][2][reg], sc_, tt));
            float y3 = hswish(fmaf(acc[fc][3][reg], sc_, tt));
            unsigned short* o = h1b + ((size_t)n * CR + co) * S1 + s0;
            *reinterpret_cast<unsigned int*>(o + 2 * ln16)      = pkbf16(y0, y1);
            *reinterpret_cast<unsigned int*>(o + 32 + 2 * ln16) = pkbf16(y2, y3);
        }
}

// ---------------------------------------------------------------------------
// Kernel B: depthwise 3x3x3 conv stride 2 pad 1 + BN2 + hswish (bf16 input)
// ---------------------------------------------------------------------------
__global__ __launch_bounds__(256) void dwconv_kernel(
    const unsigned short* __restrict__ h1b, const float* __restrict__ wdw,
    const float* __restrict__ g, const float* __restrict__ b,
    const float* __restrict__ m, const float* __restrict__ v,
    float* __restrict__ h2)
{
    __shared__ float s[T_IN][H_IN][W_IN];
    __shared__ float wl[27];
    int blk = blockIdx.x;
    int n = blk >> 7;
    int c = blk & 127;
    int tid = threadIdx.x;
    const unsigned short* in = h1b + ((size_t)n * CR + c) * S1;

    {
        int e = tid * 8;
        ushort8 u = *reinterpret_cast<const ushort8*>(in + e);
        float* sp = &s[0][0][0] + e;
        #pragma unroll
        for (int i = 0; i < 8; i++)
            sp[i] = __uint_as_float((unsigned int)(unsigned short)u[i] << 16);
    }
    if (tid < 27) wl[tid] = wdw[c * 27 + tid];
    __syncthreads();

    int wo = tid & 7;
    int ho = (tid >> 3) & 7;
    int to = tid >> 6;
    float acc = 0.0f;
    #pragma unroll
    for (int dt = 0; dt < 3; dt++) {
        int ti = 2 * to - 1 + dt;
        if (ti < 0 || ti >= T_IN) continue;
        #pragma unroll
        for (int dh = 0; dh < 3; dh++) {
            int hi = 2 * ho - 1 + dh;
            if (hi < 0 || hi >= H_IN) continue;
            #pragma unroll
            for (int dw = 0; dw < 3; dw++) {
                int wi = 2 * wo - 1 + dw;
                if (wi < 0 || wi >= W_IN) continue;
                acc = fmaf(wl[(dt * 3 + dh) * 3 + dw], s[ti][hi][wi], acc);
            }
        }
    }
    float sc = g[c] * rsqrtf(v[c] + EPSB);
    float y  = fmaf(acc, sc, fmaf(-m[c], sc, b[c]));
    h2[((size_t)n * CR + c) * S2 + tid] = hswish(y);
}

// ---------------------------------------------------------------------------
// Kernel C: 1x1x1 conv 128 -> 128 + BN3 + hswish, FUSED global-mean partials.
// ---------------------------------------------------------------------------
#define KC 16
__global__ __launch_bounds__(256) void conv2_kernel(
    const float* __restrict__ h2, const float* __restrict__ w2,
    const float* __restrict__ g, const float* __restrict__ b,
    const float* __restrict__ m, const float* __restrict__ v,
    float* __restrict__ pp)
{
    __shared__ float Xs[KC][64];
    __shared__ float Ws[KC][CR + 4];

    int blk = blockIdx.x;
    int n  = blk >> 2;
    int sq = blk & 3;
    int s0 = sq << 6;
    int tid = threadIdx.x;
    int tco = tid >> 3;
    int ts  = tid & 7;
    const float* xn = h2 + (size_t)n * CR * S2;

    float acc[4][8];
    #pragma unroll
    for (int i = 0; i < 4; i++)
        #pragma unroll
        for (int j = 0; j < 8; j++) acc[i][j] = 0.0f;

    for (int k0 = 0; k0 < CR; k0 += KC) {
        {
            int e  = tid * 4;
            int kk = e >> 6;
            int ss = e & 63;
            float4 xv = *reinterpret_cast<const float4*>(xn + (size_t)(k0 + kk) * S2 + s0 + ss);
            *reinterpret_cast<float4*>(&Xs[kk][ss]) = xv;
        }
        #pragma unroll
        for (int r = 0; r < 8; r++) {
            int e  = tid + r * 256;
            int co = e >> 4;
            int kk = e & 15;
            Ws[kk][co] = w2[co * CR + k0 + kk];
        }
        __syncthreads();
        #pragma unroll
        for (int kk = 0; kk < KC; kk++) {
            float a[4], bb[8];
            #pragma unroll
            for (int r = 0; r < 4; r++) a[r] = Ws[kk][tco * 4 + r];
            #pragma unroll
            for (int q = 0; q < 8; q++) bb[q] = Xs[kk][ts * 8 + q];
            #pragma unroll
            for (int r = 0; r < 4; r++)
                #pragma unroll
                for (int q = 0; q < 8; q++)
                    acc[r][q] = fmaf(a[r], bb[q], acc[r][q]);
        }
        __syncthreads();
    }

    #pragma unroll
    for (int r = 0; r < 4; r++) {
        int co = tco * 4 + r;
        float sc = g[co] * rsqrtf(v[co] + EPSB);
        float tt = fmaf(-m[co], sc, b[co]);
        float psum = 0.0f;
        #pragma unroll
        for (int q = 0; q < 8; q++)
            psum += hswish(fmaf(acc[r][q], sc, tt));
        #pragma unroll
        for (int off = 4; off > 0; off >>= 1)
            psum += __shfl_down(psum, off, 8);
        if (ts == 0)
            pp[((size_t)n * CR + co) * 4 + sq] = psum;
    }
}

// ---------------------------------------------------------------------------
// Kernel E: head — pooled mean from partials, 1x1 conv 128->6 + BN4 +
// sigmoid -> ROI boxes [n][6].  One block per n.
// ---------------------------------------------------------------------------
__global__ __launch_bounds__(128) void head_kernel(
    const float* __restrict__ pp, const float* __restrict__ w3,
    const float* __restrict__ g, const float* __restrict__ b,
    const float* __restrict__ m, const float* __restrict__ v,
    float* __restrict__ boxes)
{
    __shared__ float red[2];
    int n = blockIdx.x;
    int c = threadIdx.x;          // 0..127
    int wave = c >> 6, lane = c & 63;
    const float* p = pp + ((size_t)n * CR + c) * 4;
    float pc = (p[0] + p[1] + p[2] + p[3]) * (1.0f / 256.0f);

    for (int j = 0; j < 6; j++) {
        float t = w3[j * CR + c] * pc;
        #pragma unroll
        for (int off = 32; off > 0; off >>= 1)
            t += __shfl_down(t, off, 64);
        if (lane == 0) red[wave] = t;
        __syncthreads();
        if (c == 0) {
            float acc = red[0] + red[1];
            float sc = g[j] * rsqrtf(v[j] + EPSB);
            float logit = fmaf(acc, sc, fmaf(-m[j], sc, b[j]));
            float lim = 1.0f / (1.0f + expf(-logit));
            float scale = ((j % 3) == 2) ? 8.0f : 16.0f;
            float val = (j < 3) ? 0.5f * lim * scale : (1.0f - 0.5f * lim) * scale;
            boxes[n * 6 + j] = val;
        }
        __syncthreads();
    }
}

// ---------------------------------------------------------------------------
// Kernel F: 3D ROI align of x.  One block per (n,c); slice in LDS.
// ---------------------------------------------------------------------------
__global__ __launch_bounds__(256) void roi_kernel(
    const float* __restrict__ x, const float* __restrict__ boxes,
    float* __restrict__ out)
{
    __shared__ float s[T_IN][H_IN][W_IN];
    __shared__ float box[6];
    int blk = blockIdx.x;
    int n = blk >> 8;
    int c = blk & 255;
    int tid = threadIdx.x;
    const float* in = x + ((size_t)n * CIN + c) * S1;
    #pragma unroll
    for (int r = 0; r < 2; r++) {
        int e = (tid + r * 256) * 4;
        *reinterpret_cast<float4*>(&s[0][0][0] + e) =
            *reinterpret_cast<const float4*>(in + e);
    }
    if (tid < 6) box[tid] = boxes[n * 6 + tid];
    __syncthreads();

    if (tid < PT * PH * PW) {
        int pw = tid % 7;
        int ph = (tid / 7) % 7;
        int pt = tid / 49;
        float sx = box[0], sy = box[1], st = box[2];
        float bszx = fmaxf(box[3] - sx, 1.0f) * (1.0f / PW);
        float bszy = fmaxf(box[4] - sy, 1.0f) * (1.0f / PH);
        float bszt = fmaxf(box[5] - st, 1.0f) * (1.0f / PT);

        float acc = 0.0f;
        #pragma unroll
        for (int it = 0; it < 2; it++) {
            float tc = st + ((float)(pt * 2 + it) + 0.5f) * 0.5f * bszt;
            tc = fminf(fmaxf(tc, 0.0f), (float)(T_IN - 1));
            int tlo = (int)floorf(tc);
            int thi = min(tlo + 1, T_IN - 1);
            float tw = tc - (float)tlo;
            #pragma unroll
            for (int iy = 0; iy < 2; iy++) {
                float yc = sy + ((float)(ph * 2 + iy) + 0.5f) * 0.5f * bszy;
                yc = fminf(fmaxf(yc, 0.0f), (float)(H_IN - 1));
                int ylo = (int)floorf(yc);
                int yhi = min(ylo + 1, H_IN - 1);
                float yw = yc - (float)ylo;
                #pragma unroll
                for (int ix = 0; ix < 2; ix++) {
                    float xc = sx + ((float)(pw * 2 + ix) + 0.5f) * 0.5f * bszx;
                    xc = fminf(fmaxf(xc, 0.0f), (float)(W_IN - 1));
                    int xlo = (int)floorf(xc);
                    int xhi = min(xlo + 1, W_IN - 1);
                    float xw = xc - (float)xlo;

                    float v00 = s[tlo][ylo][xlo] * (1.0f - xw) + s[tlo][ylo][xhi] * xw;
                    float v01 = s[tlo][yhi][xlo] * (1.0f - xw) + s[tlo][yhi][xhi] * xw;
                    float v10 = s[thi][ylo][xlo] * (1.0f - xw) + s[thi][ylo][xhi] * xw;
                    float v11 = s[thi][yhi][xlo] * (1.0f - xw) + s[thi][yhi][xhi] * xw;
                    float v0 = v00 * (1.0f - yw) + v01 * yw;
                    float v1 = v10 * (1.0f - yw) + v11 * yw;
                    acc += v0 * (1.0f - tw) + v1 * tw;
                }
            }
        }
        out[(((size_t)(n * CIN + c) * PT + pt) * PH + ph) * PW + pw] = acc * 0.125f;
    }
}

// ---------------------------------------------------------------------------
extern "C" void kernel_launch(void* const* d_in, const int* in_sizes, int n_in,
                              void* d_out, int out_size, void* d_ws, size_t ws_size,
                              hipStream_t stream) {
    const float* x   = (const float*)d_in[0];
    const float* w1  = (const float*)d_in[1];
    const float* g1  = (const float*)d_in[2];
    const float* b1  = (const float*)d_in[3];
    const float* m1  = (const float*)d_in[4];
    const float* v1  = (const float*)d_in[5];
    const float* wdw = (const float*)d_in[6];
    const float* g2  = (const float*)d_in[7];
    const float* b2  = (const float*)d_in[8];
    const float* m2  = (const float*)d_in[9];
    const float* v2  = (const float*)d_in[10];
    const float* w2  = (const float*)d_in[11];
    const float* g3  = (const float*)d_in[12];
    const float* b3  = (const float*)d_in[13];
    const float* m3  = (const float*)d_in[14];
    const float* v3  = (const float*)d_in[15];
    const float* w3  = (const float*)d_in[16];
    const float* g4  = (const float*)d_in[17];
    const float* b4  = (const float*)d_in[18];
    const float* m4  = (const float*)d_in[19];
    const float* v4  = (const float*)d_in[20];

    float* ws = (float*)d_ws;
    float* h1     = ws;                                   // bf16 h1 (ushort)
    float* h2     = h1 + (size_t)N_BATCH * CR * S1;       // 2,097,152 f
    float* h3     = h2 + (size_t)N_BATCH * CR * S2;       // region reused for whi/wlo
    float* pp     = h3 + (size_t)N_BATCH * CR * S2;       // 32,768 f pooled partials
    float* boxes  = pp + (size_t)N_BATCH * CR * 4;        // 384 f
    unsigned short* h1b = (unsigned short*)h1;
    unsigned short* whi = (unsigned short*)h3;            // 32768 u16
    unsigned short* wlo = whi + CR * CIN;                 // 32768 u16

    wsplit_kernel<<<dim3(128), dim3(256), 0, stream>>>(w1, whi, wlo, pp);
    conv1_mfma_kernel<<<dim3(2048), dim3(256), 0, stream>>>(x, whi, wlo, g1, b1, m1, v1, h1b);
    dwconv_kernel<<<dim3(N_BATCH * CR), dim3(256), 0, stream>>>(h1b, wdw, g2, b2, m2, v2, h2);
    conv2_kernel<<<dim3(256), dim3(256), 0, stream>>>(h2, w2, g3, b3, m3, v3, pp);
    head_kernel<<<dim3(N_BATCH), dim3(128), 0, stream>>>(pp, w3, g4, b4, m4, v4, boxes);
    roi_kernel<<<dim3(N_BATCH * CIN), dim3(256), 0, stream>>>(x, boxes, (float*)d_out);
}